// Round 1
// baseline (350.490 us; speedup 1.0000x reference)
//
#include <hip/hip_runtime.h>
#include <hip/hip_bf16.h>
#include <math.h>

typedef __bf16 bf16_t;
typedef __bf16 bf16x8 __attribute__((ext_vector_type(8)));
typedef float f32x4 __attribute__((ext_vector_type(4)));

#define QEPS 1e-5

__device__ __forceinline__ void gload_lds16(const void* g, void* l) {
  __builtin_amdgcn_global_load_lds((const __attribute__((address_space(1))) void*)g,
                                   (__attribute__((address_space(3))) void*)l, 16, 0, 0);
}

// ---- fp64 sum of |w| ----
__global__ void reduce_abs_kernel(const float* __restrict__ w, int n, double* __restrict__ out) {
  double s = 0.0;
  int stride = gridDim.x * blockDim.x;
  for (int i = blockIdx.x * blockDim.x + threadIdx.x; i < n; i += stride)
    s += (double)fabsf(w[i]);
  for (int off = 32; off > 0; off >>= 1)
    s += __shfl_down(s, off, 64);
  __shared__ double ls[4];
  int lane = threadIdx.x & 63, wv = threadIdx.x >> 6;
  if (lane == 0) ls[wv] = s;
  __syncthreads();
  if (threadIdx.x == 0) {
    double t = ls[0] + ls[1] + ls[2] + ls[3];
    atomicAdd(out, t);
  }
}

// ---- fp64 quantize decision -> ternary bf16 {-1,0,+1} ----
__global__ void quantize_kernel(const float* __restrict__ w, int n,
                                const double* __restrict__ sum, double cnt,
                                bf16_t* __restrict__ q) {
  int i = blockIdx.x * blockDim.x + threadIdx.x;
  if (i >= n) return;
  double g = sum[0] / cnt + QEPS;
  double t = (double)w[i] / g;
  double r = rint(t);            // round-half-even, matches np.round
  r = fmin(1.0, fmax(-1.0, r));
  q[i] = (bf16_t)(float)r;
}

// ---- cast x -> bf16, zero-pad rows to Mpad ----
__global__ void cast_pad_kernel(const float* __restrict__ x, bf16_t* __restrict__ xb,
                                long long nvalid, long long ntotal) {
  long long i = (long long)blockIdx.x * blockDim.x + threadIdx.x;
  if (i < ntotal) xb[i] = (i < nvalid) ? (bf16_t)x[i] : (bf16_t)0.0f;
}

// ---- C = A(M x K) * B(N x K)^T, bf16 MFMA 16x16x32, 128x128 tile, BK=32 ----
// EPI==0: out = bf16( gelu(gamma*acc + bias) )   (ld = N)
// EPI==1: out = fp32( gamma*acc + bias ), rows < Mvalid only
template <int EPI>
__global__ __launch_bounds__(256, 2)
void gemm_bt_kernel(const bf16_t* __restrict__ A, const bf16_t* __restrict__ B,
                    const float* __restrict__ bias,
                    const double* __restrict__ sumptr, double cnt,
                    void* __restrict__ Cout, int N, int K, int Mvalid) {
  __shared__ bf16_t sA[128 * 32];   // 8 KB
  __shared__ bf16_t sB[128 * 32];   // 8 KB
  const int tid = threadIdx.x;
  const int lane = tid & 63;
  const int wave = tid >> 6;         // 4 waves, 2x2 layout of 64x64 regions
  const int wr = (wave >> 1) * 64;
  const int wc = (wave & 1) * 64;
  const int row16 = lane & 15;
  const int quad = lane >> 4;

  const size_t Ks = (size_t)K;
  // staging: thread t covers row (t>>2), 16B chunk (t&3); round1 adds 64 rows
  const bf16_t* gA = A + ((size_t)(blockIdx.y * 128 + (tid >> 2))) * Ks + (size_t)(tid & 3) * 8;
  const bf16_t* gB = B + ((size_t)(blockIdx.x * 128 + (tid >> 2))) * Ks + (size_t)(tid & 3) * 8;
  bf16_t* lA0 = sA + wave * 512;          // wave-uniform LDS bases (bytes: wave*1024)
  bf16_t* lA1 = sA + 2048 + wave * 512;   // +4096 B
  bf16_t* lB0 = sB + wave * 512;
  bf16_t* lB1 = sB + 2048 + wave * 512;

  f32x4 acc[4][4] = {};

  for (int k0 = 0; k0 < K; k0 += 32) {
    gload_lds16(gA, lA0);
    gload_lds16(gA + 64 * Ks, lA1);
    gload_lds16(gB, lB0);
    gload_lds16(gB + 64 * Ks, lB1);
    gA += 32;
    gB += 32;
    __syncthreads();   // compiler emits vmcnt(0) drain here

    bf16x8 afr[4], bfr[4];
#pragma unroll
    for (int i = 0; i < 4; i++)
      afr[i] = *(const bf16x8*)&sA[(wr + i * 16 + row16) * 32 + quad * 8];
#pragma unroll
    for (int j = 0; j < 4; j++)
      bfr[j] = *(const bf16x8*)&sB[(wc + j * 16 + row16) * 32 + quad * 8];
#pragma unroll
    for (int i = 0; i < 4; i++)
#pragma unroll
      for (int j = 0; j < 4; j++)
        acc[i][j] = __builtin_amdgcn_mfma_f32_16x16x32_bf16(afr[i], bfr[j], acc[i][j], 0, 0, 0);
    __syncthreads();
  }

  const float gamma = (float)(sumptr[0] / cnt + QEPS);
  const int c_base = blockIdx.x * 128 + wc + row16;   // C/D: col = lane&15
  const int r_base = blockIdx.y * 128 + wr + quad * 4; // row = quad*4 + reg
#pragma unroll
  for (int j = 0; j < 4; j++) {
    const int col = c_base + j * 16;
    const float bv = bias[col];
#pragma unroll
    for (int i = 0; i < 4; i++) {
#pragma unroll
      for (int r = 0; r < 4; r++) {
        const int row = r_base + i * 16 + r;
        float v = gamma * acc[i][j][r] + bv;
        if (EPI == 0) {
          v = 0.5f * v * (1.0f + erff(v * 0.7071067811865476f));  // exact GELU
          ((bf16_t*)Cout)[(size_t)row * N + col] = (bf16_t)v;
        } else {
          if (row < Mvalid)
            ((float*)Cout)[(size_t)row * N + col] = v;
        }
      }
    }
  }
}

extern "C" void kernel_launch(void* const* d_in, const int* in_sizes, int n_in,
                              void* d_out, int out_size, void* d_ws, size_t ws_size,
                              hipStream_t stream) {
  const float* x  = (const float*)d_in[0];
  const float* w1 = (const float*)d_in[1];
  const float* b1 = (const float*)d_in[2];
  const float* w2 = (const float*)d_in[3];
  const float* b2 = (const float*)d_in[4];
  float* out = (float*)d_out;

  const int M = 64 * 197;      // 12608
  const int Mpad = 12672;      // 99 * 128
  const int D = 768, H = 3072;
  const int nW = H * D;        // 2359296 (both weights)

  char* ws = (char*)d_ws;
  double* sums = (double*)ws;                      // [0]=sum|w1|, [1]=sum|w2|
  bf16_t* xb  = (bf16_t*)(ws + 256);               // Mpad x D
  bf16_t* w1q = xb + (size_t)Mpad * D;             // H x D
  bf16_t* w2q = w1q + (size_t)H * D;               // D x H
  bf16_t* hb  = w2q + (size_t)D * H;               // Mpad x H
  // total ws use ~102 MB

  hipMemsetAsync(sums, 0, 2 * sizeof(double), stream);
  reduce_abs_kernel<<<512, 256, 0, stream>>>(w1, nW, sums + 0);
  reduce_abs_kernel<<<512, 256, 0, stream>>>(w2, nW, sums + 1);
  quantize_kernel<<<nW / 256, 256, 0, stream>>>(w1, nW, sums + 0, (double)nW, w1q);
  quantize_kernel<<<nW / 256, 256, 0, stream>>>(w2, nW, sums + 1, (double)nW, w2q);
  cast_pad_kernel<<<((long long)Mpad * D) / 256, 256, 0, stream>>>(
      x, xb, (long long)M * D, (long long)Mpad * D);

  dim3 g1(H / 128, Mpad / 128);   // 24 x 99
  gemm_bt_kernel<0><<<g1, 256, 0, stream>>>(xb, w1q, b1, sums + 0, (double)nW, hb, H, D, M);
  dim3 g2(D / 128, Mpad / 128);   // 6 x 99
  gemm_bt_kernel<1><<<g2, 256, 0, stream>>>(hb, w2q, b2, sums + 1, (double)nW, out, D, H, M);
}

// Round 3
// 288.454 us; speedup vs baseline: 1.2151x; 1.2151x over previous
//
#include <hip/hip_runtime.h>
#include <hip/hip_bf16.h>
#include <math.h>

typedef __bf16 bf16_t;
typedef __bf16 bf16x8 __attribute__((ext_vector_type(8)));
typedef __bf16 bf16x4 __attribute__((ext_vector_type(4)));
typedef float f32x4 __attribute__((ext_vector_type(4)));

#define QEPS 1e-5

__device__ __forceinline__ void gload_lds16(const void* g, void* l) {
  __builtin_amdgcn_global_load_lds((const __attribute__((address_space(1))) void*)g,
                                   (__attribute__((address_space(3))) void*)l, 16, 0, 0);
}

// exact GELU via A&S 7.1.26 erf (|err| <= 1.5e-7), branchless, v_exp/v_rcp
__device__ __forceinline__ float gelu_exact(float x) {
  float a = x * 0.7071067811865476f;
  float s = fabsf(a);
  float t = __builtin_amdgcn_rcpf(__builtin_fmaf(0.3275911f, s, 1.0f));
  float p = __builtin_fmaf(1.061405429f, t, -1.453152027f);
  p = __builtin_fmaf(p, t, 1.421413741f);
  p = __builtin_fmaf(p, t, -0.284496736f);
  p = __builtin_fmaf(p, t, 0.254829592f);
  p = p * t;
  float e = __expf(-s * s);
  float er = copysignf(__builtin_fmaf(-p, e, 1.0f), a);
  return 0.5f * x * (1.0f + er);
}

// ---- fp64 sum of |w| for both weights in one launch ----
__global__ void reduce_abs2_kernel(const float* __restrict__ w1, const float* __restrict__ w2,
                                   int n, double* __restrict__ out) {
  const int nb = gridDim.x >> 1;
  const bool second = blockIdx.x >= nb;
  const float* __restrict__ w = second ? w2 : w1;
  const int b = second ? blockIdx.x - nb : blockIdx.x;
  double s = 0.0;
  const int stride = nb * blockDim.x * 4;
  for (int i = (b * blockDim.x + threadIdx.x) * 4; i < n; i += stride) {
    float4 v = *(const float4*)(w + i);
    s += (double)fabsf(v.x) + (double)fabsf(v.y) + (double)fabsf(v.z) + (double)fabsf(v.w);
  }
  for (int off = 32; off > 0; off >>= 1)
    s += __shfl_down(s, off, 64);
  __shared__ double ls[4];
  int lane = threadIdx.x & 63, wv = threadIdx.x >> 6;
  if (lane == 0) ls[wv] = s;
  __syncthreads();
  if (threadIdx.x == 0)
    atomicAdd(out + (second ? 1 : 0), ls[0] + ls[1] + ls[2] + ls[3]);
}

// ---- fp64 quantize decision -> ternary bf16, both weights, float4 vectorized ----
__global__ void quantize2_kernel(const float* __restrict__ w1, const float* __restrict__ w2,
                                 int n, const double* __restrict__ sums, double cnt,
                                 bf16_t* __restrict__ q1, bf16_t* __restrict__ q2) {
  int i4 = blockIdx.x * blockDim.x + threadIdx.x;
  const int half4 = n >> 2;
  const float* w;
  bf16_t* q;
  double g;
  int idx;
  if (i4 < half4) { w = w1; q = q1; g = sums[0]; idx = i4; }
  else            { w = w2; q = q2; g = sums[1]; idx = i4 - half4; }
  g = g / cnt + QEPS;
  float4 v = ((const float4*)w)[idx];
  bf16x4 r;
  {
    double t0 = fmin(1.0, fmax(-1.0, rint((double)v.x / g)));
    double t1 = fmin(1.0, fmax(-1.0, rint((double)v.y / g)));
    double t2 = fmin(1.0, fmax(-1.0, rint((double)v.z / g)));
    double t3 = fmin(1.0, fmax(-1.0, rint((double)v.w / g)));
    r[0] = (bf16_t)(float)t0; r[1] = (bf16_t)(float)t1;
    r[2] = (bf16_t)(float)t2; r[3] = (bf16_t)(float)t3;
  }
  ((bf16x4*)q)[idx] = r;
}

// ---- cast x -> bf16, zero-pad rows to Mpad, float4 vectorized ----
__global__ void cast_pad_kernel(const float* __restrict__ x, bf16_t* __restrict__ xb,
                                long long nvalid, long long ntotal) {
  long long i = ((long long)blockIdx.x * blockDim.x + threadIdx.x) * 4;
  if (i >= ntotal) return;
  bf16x4 r;
  if (i < nvalid) {
    float4 v = *(const float4*)(x + i);
    r[0] = (bf16_t)v.x; r[1] = (bf16_t)v.y; r[2] = (bf16_t)v.z; r[3] = (bf16_t)v.w;
  } else {
    r[0] = (bf16_t)0.0f; r[1] = (bf16_t)0.0f; r[2] = (bf16_t)0.0f; r[3] = (bf16_t)0.0f;
  }
  *(bf16x4*)(xb + i) = r;
}

// ---- C = A(M x K) * B(N x K)^T, bf16 MFMA 16x16x32, 128x128 tile, BK=64 ----
// LDS layout: row stride 64 elems (128 B = full bank line); 16B chunk c of row r
// stored at slot (c ^ (r & 7)) -> 2-way max bank aliasing (free).
// EPI==0: h = bf16(gelu(gamma*acc + bias)), coalesced via LDS-staged stores
// EPI==1: out = fp32(gamma*acc + bias), rows < Mvalid
template <int EPI>
__global__ __launch_bounds__(256, 2)
void gemm_bt_kernel(const bf16_t* __restrict__ A, const bf16_t* __restrict__ B,
                    const float* __restrict__ bias,
                    const double* __restrict__ sumptr, double cnt,
                    void* __restrict__ Cout, int N, int K, int Mvalid) {
  __shared__ bf16_t sA[128 * 64];   // 16 KB
  __shared__ bf16_t sB[128 * 64];   // 16 KB
  const int tid = threadIdx.x;
  const int lane = tid & 63;
  const int wave = tid >> 6;          // 4 waves, 2x2 of 64x64 regions
  const int wr = (wave >> 1) * 64;
  const int wc = (wave & 1) * 64;
  const int row16 = lane & 15;
  const int quad = lane >> 4;

  const size_t Ks = (size_t)K;
  // staging: thread t covers row (t>>3) (+32 per round), swizzled chunk
  const int slot = tid & 7;
  const int cg = slot ^ ((tid >> 3) & 7);       // global 16B chunk to fetch
  const bf16_t* gA = A + ((size_t)(blockIdx.y * 128 + (tid >> 3))) * Ks + (size_t)cg * 8;
  const bf16_t* gB = B + ((size_t)(blockIdx.x * 128 + (tid >> 3))) * Ks + (size_t)cg * 8;
  bf16_t* lA = sA + wave * 512;   // + n*2048 per round; builtin adds lane*16B
  bf16_t* lB = sB + wave * 512;

  f32x4 acc[4][4] = {};

  for (int k0 = 0; k0 < K; k0 += 64) {
#pragma unroll
    for (int n = 0; n < 4; n++) {
      gload_lds16(gA + (size_t)(n * 32) * Ks, lA + n * 2048);
      gload_lds16(gB + (size_t)(n * 32) * Ks, lB + n * 2048);
    }
    gA += 64;
    gB += 64;
    __syncthreads();

#pragma unroll
    for (int kk = 0; kk < 2; kk++) {
      bf16x8 afr[4], bfr[4];
      const int swz = ((kk * 4 + quad) ^ (row16 & 7)) * 8;
#pragma unroll
      for (int i = 0; i < 4; i++)
        afr[i] = *(const bf16x8*)&sA[(wr + i * 16 + row16) * 64 + swz];
#pragma unroll
      for (int j = 0; j < 4; j++)
        bfr[j] = *(const bf16x8*)&sB[(wc + j * 16 + row16) * 64 + swz];
#pragma unroll
      for (int i = 0; i < 4; i++)
#pragma unroll
        for (int j = 0; j < 4; j++)
          acc[i][j] = __builtin_amdgcn_mfma_f32_16x16x32_bf16(afr[i], bfr[j], acc[i][j], 0, 0, 0);
    }
    __syncthreads();
  }

  const float gamma = (float)(sumptr[0] / cnt + QEPS);
  const int c_base = blockIdx.x * 128 + wc + row16;    // C/D: col = lane&15
  const int r_base = blockIdx.y * 128 + wr + quad * 4; // row = quad*4 + reg

  if constexpr (EPI == 0) {
    // LDS-staged coalesced bf16 stores: 4 passes of 32 rows (136-elem stride pad)
    __shared__ bf16_t sE[32 * 136];   // 8.5 KB
    float bv[4];
#pragma unroll
    for (int j = 0; j < 4; j++) bv[j] = bias[c_base + j * 16];
    bf16_t* h = (bf16_t*)Cout;
#pragma unroll
    for (int i = 0; i < 4; i++) {
#pragma unroll
      for (int j = 0; j < 4; j++) {
        const int col = wc + j * 16 + row16;
#pragma unroll
        for (int r = 0; r < 4; r++) {
          const int e = (wave >> 1) * 16 + quad * 4 + r;
          float v = gelu_exact(gamma * acc[i][j][r] + bv[j]);
          sE[e * 136 + col] = (bf16_t)v;
        }
      }
      __syncthreads();
      {
        // 32 rows x 128 cols = 8 KB per pass; 256 threads x 32 B each
        const int e = tid >> 3, ch = tid & 7;
        const int grow = blockIdx.y * 128 + (e >> 4) * 64 + i * 16 + (e & 15);
        bf16_t* dst = &h[(size_t)grow * N + blockIdx.x * 128];
        *(bf16x8*)&dst[ch * 8] = *(const bf16x8*)&sE[e * 136 + ch * 8];
        *(bf16x8*)&dst[ch * 8 + 64] = *(const bf16x8*)&sE[e * 136 + ch * 8 + 64];
      }
      __syncthreads();
    }
  } else {
    float* out = (float*)Cout;
#pragma unroll
    for (int j = 0; j < 4; j++) {
      const int col = c_base + j * 16;
      const float bv = bias[col];
#pragma unroll
      for (int i = 0; i < 4; i++) {
#pragma unroll
        for (int r = 0; r < 4; r++) {
          const int row = r_base + i * 16 + r;
          if (row < Mvalid)
            out[(size_t)row * N + col] = gamma * acc[i][j][r] + bv;
        }
      }
    }
  }
}

extern "C" void kernel_launch(void* const* d_in, const int* in_sizes, int n_in,
                              void* d_out, int out_size, void* d_ws, size_t ws_size,
                              hipStream_t stream) {
  const float* x  = (const float*)d_in[0];
  const float* w1 = (const float*)d_in[1];
  const float* b1 = (const float*)d_in[2];
  const float* w2 = (const float*)d_in[3];
  const float* b2 = (const float*)d_in[4];
  float* out = (float*)d_out;

  const int M = 64 * 197;      // 12608
  const int Mpad = 12672;      // 99 * 128
  const int D = 768, H = 3072;
  const int nW = H * D;        // 2359296

  char* ws = (char*)d_ws;
  double* sums = (double*)ws;                      // [0]=sum|w1|, [1]=sum|w2|
  bf16_t* xb  = (bf16_t*)(ws + 256);               // Mpad x D
  bf16_t* w1q = xb + (size_t)Mpad * D;             // H x D
  bf16_t* w2q = w1q + (size_t)H * D;               // D x H
  bf16_t* hb  = w2q + (size_t)D * H;               // Mpad x H

  hipMemsetAsync(sums, 0, 2 * sizeof(double), stream);
  reduce_abs2_kernel<<<512, 256, 0, stream>>>(w1, w2, nW, sums);
  quantize2_kernel<<<(2 * nW / 4) / 256, 256, 0, stream>>>(w1, w2, nW, sums, (double)nW, w1q, w2q);
  cast_pad_kernel<<<((long long)Mpad * D / 4) / 256, 256, 0, stream>>>(
      x, xb, (long long)M * D, (long long)Mpad * D);

  dim3 g1(H / 128, Mpad / 128);   // 24 x 99
  gemm_bt_kernel<0><<<g1, 256, 0, stream>>>(xb, w1q, b1, sums + 0, (double)nW, hb, H, D, M);
  dim3 g2(D / 128, Mpad / 128);   // 6 x 99
  gemm_bt_kernel<1><<<g2, 256, 0, stream>>>(hb, w2q, b2, sums + 1, (double)nW, out, D, H, M);
}

// Round 4
// 262.714 us; speedup vs baseline: 1.3341x; 1.0980x over previous
//
#include <hip/hip_runtime.h>
#include <hip/hip_bf16.h>
#include <math.h>

typedef __bf16 bf16_t;
typedef __bf16 bf16x8 __attribute__((ext_vector_type(8)));
typedef __bf16 bf16x4 __attribute__((ext_vector_type(4)));
typedef float f32x4 __attribute__((ext_vector_type(4)));

#define QEPS 1e-5

__device__ __forceinline__ void gload_lds16(const void* g, void* l) {
  __builtin_amdgcn_global_load_lds((const __attribute__((address_space(1))) void*)g,
                                   (__attribute__((address_space(3))) void*)l, 16, 0, 0);
}

// exact GELU via A&S 7.1.26 erf (|err| <= 1.5e-7), branchless, v_exp/v_rcp
__device__ __forceinline__ float gelu_exact(float x) {
  float a = x * 0.7071067811865476f;
  float s = fabsf(a);
  float t = __builtin_amdgcn_rcpf(__builtin_fmaf(0.3275911f, s, 1.0f));
  float p = __builtin_fmaf(1.061405429f, t, -1.453152027f);
  p = __builtin_fmaf(p, t, 1.421413741f);
  p = __builtin_fmaf(p, t, -0.284496736f);
  p = __builtin_fmaf(p, t, 0.254829592f);
  p = p * t;
  float e = __expf(-s * s);
  float er = copysignf(__builtin_fmaf(-p, e, 1.0f), a);
  return 0.5f * x * (1.0f + er);
}

// ---- fp64 sum of |w| for both weights in one launch ----
__global__ void reduce_abs2_kernel(const float* __restrict__ w1, const float* __restrict__ w2,
                                   int n, double* __restrict__ out) {
  const int nb = gridDim.x >> 1;
  const bool second = blockIdx.x >= nb;
  const float* __restrict__ w = second ? w2 : w1;
  const int b = second ? blockIdx.x - nb : blockIdx.x;
  double s = 0.0;
  const int stride = nb * blockDim.x * 4;
  for (int i = (b * blockDim.x + threadIdx.x) * 4; i < n; i += stride) {
    float4 v = *(const float4*)(w + i);
    s += (double)fabsf(v.x) + (double)fabsf(v.y) + (double)fabsf(v.z) + (double)fabsf(v.w);
  }
  for (int off = 32; off > 0; off >>= 1)
    s += __shfl_down(s, off, 64);
  __shared__ double ls[4];
  int lane = threadIdx.x & 63, wv = threadIdx.x >> 6;
  if (lane == 0) ls[wv] = s;
  __syncthreads();
  if (threadIdx.x == 0)
    atomicAdd(out + (second ? 1 : 0), ls[0] + ls[1] + ls[2] + ls[3]);
}

// ---- fp64 quantize decision -> ternary bf16, both weights, float4 vectorized ----
__global__ void quantize2_kernel(const float* __restrict__ w1, const float* __restrict__ w2,
                                 int n, const double* __restrict__ sums, double cnt,
                                 bf16_t* __restrict__ q1, bf16_t* __restrict__ q2) {
  int i4 = blockIdx.x * blockDim.x + threadIdx.x;
  const int half4 = n >> 2;
  const float* w;
  bf16_t* q;
  double g;
  int idx;
  if (i4 < half4) { w = w1; q = q1; g = sums[0]; idx = i4; }
  else            { w = w2; q = q2; g = sums[1]; idx = i4 - half4; }
  g = g / cnt + QEPS;
  float4 v = ((const float4*)w)[idx];
  bf16x4 r;
  {
    double t0 = fmin(1.0, fmax(-1.0, rint((double)v.x / g)));
    double t1 = fmin(1.0, fmax(-1.0, rint((double)v.y / g)));
    double t2 = fmin(1.0, fmax(-1.0, rint((double)v.z / g)));
    double t3 = fmin(1.0, fmax(-1.0, rint((double)v.w / g)));
    r[0] = (bf16_t)(float)t0; r[1] = (bf16_t)(float)t1;
    r[2] = (bf16_t)(float)t2; r[3] = (bf16_t)(float)t3;
  }
  ((bf16x4*)q)[idx] = r;
}

// ---- cast x -> bf16, zero-pad rows to Mpad, float4 vectorized ----
__global__ void cast_pad_kernel(const float* __restrict__ x, bf16_t* __restrict__ xb,
                                long long nvalid, long long ntotal) {
  long long i = ((long long)blockIdx.x * blockDim.x + threadIdx.x) * 4;
  if (i >= ntotal) return;
  bf16x4 r;
  if (i < nvalid) {
    float4 v = *(const float4*)(x + i);
    r[0] = (bf16_t)v.x; r[1] = (bf16_t)v.y; r[2] = (bf16_t)v.z; r[3] = (bf16_t)v.w;
  } else {
    r[0] = (bf16_t)0.0f; r[1] = (bf16_t)0.0f; r[2] = (bf16_t)0.0f; r[3] = (bf16_t)0.0f;
  }
  *(bf16x4*)(xb + i) = r;
}

// ---- C = A(M x K) * B(N x K)^T, bf16 MFMA 16x16x32, 128x128 tile, BK=64 ----
// 1D grid, XCD-chunked tile mapping: block f runs on XCD f%8 (round-robin
// dispatch); give each XCD a contiguous row-major chunk of tiles so each
// A row-tile lives in one XCD's L2 (cuts cross-XCD re-fetch of A).
// LDS: row stride 64 elems; 16B chunk c of row r at slot (c ^ (r&7)) -> conflict-free.
// EPI==0: h = bf16(gelu(gamma*acc + bias)), coalesced via LDS-staged stores
// EPI==1: out = fp32(gamma*acc + bias), rows < Mvalid
template <int EPI>
__global__ __launch_bounds__(256, 4)
void gemm_bt_kernel(const bf16_t* __restrict__ A, const bf16_t* __restrict__ B,
                    const float* __restrict__ bias,
                    const double* __restrict__ sumptr, double cnt,
                    void* __restrict__ Cout, int N, int K, int Mvalid, int gx) {
  __shared__ bf16_t sA[128 * 64];   // 16 KB
  __shared__ bf16_t sB[128 * 64];   // 16 KB

  // XCD-chunked tile id
  const int G = gridDim.x;
  const int f = blockIdx.x;
  const int xcd = f & 7;
  const int idx = f >> 3;
  const int q8 = G >> 3, r8 = G & 7;
  const int t = xcd * q8 + (xcd < r8 ? xcd : r8) + idx;
  const int bx = t % gx;
  const int by = t / gx;

  const int tid = threadIdx.x;
  const int lane = tid & 63;
  const int wave = tid >> 6;          // 4 waves, 2x2 of 64x64 regions
  const int wr = (wave >> 1) * 64;
  const int wc = (wave & 1) * 64;
  const int row16 = lane & 15;
  const int quad = lane >> 4;

  const size_t Ks = (size_t)K;
  // staging: thread tt covers row (tt>>3) (+32 per round), swizzled chunk
  const int slot = tid & 7;
  const int cg = slot ^ ((tid >> 3) & 7);       // global 16B chunk to fetch
  const bf16_t* gA = A + ((size_t)(by * 128 + (tid >> 3))) * Ks + (size_t)cg * 8;
  const bf16_t* gB = B + ((size_t)(bx * 128 + (tid >> 3))) * Ks + (size_t)cg * 8;
  bf16_t* lA = sA + wave * 512;   // + n*2048 per round; builtin adds lane*16B
  bf16_t* lB = sB + wave * 512;

  f32x4 acc[4][4] = {};

  for (int k0 = 0; k0 < K; k0 += 64) {
#pragma unroll
    for (int n = 0; n < 4; n++) {
      gload_lds16(gA + (size_t)(n * 32) * Ks, lA + n * 2048);
      gload_lds16(gB + (size_t)(n * 32) * Ks, lB + n * 2048);
    }
    gA += 64;
    gB += 64;
    __syncthreads();

#pragma unroll
    for (int kk = 0; kk < 2; kk++) {
      bf16x8 afr[4], bfr[4];
      const int swz = ((kk * 4 + quad) ^ (row16 & 7)) * 8;
#pragma unroll
      for (int i = 0; i < 4; i++)
        afr[i] = *(const bf16x8*)&sA[(wr + i * 16 + row16) * 64 + swz];
#pragma unroll
      for (int j = 0; j < 4; j++)
        bfr[j] = *(const bf16x8*)&sB[(wc + j * 16 + row16) * 64 + swz];
#pragma unroll
      for (int i = 0; i < 4; i++)
#pragma unroll
        for (int j = 0; j < 4; j++)
          acc[i][j] = __builtin_amdgcn_mfma_f32_16x16x32_bf16(afr[i], bfr[j], acc[i][j], 0, 0, 0);
    }
    __syncthreads();
  }

  const float gamma = (float)(sumptr[0] / cnt + QEPS);
  const int c_base = bx * 128 + wc + row16;    // C/D: col = lane&15
  const int r_base = by * 128 + wr + quad * 4; // row = quad*4 + reg

  if constexpr (EPI == 0) {
    // LDS-staged coalesced bf16 stores, sE aliased onto sA (done with main loop)
    bf16_t* sE = sA;   // 32 x 136 = 8.5 KB <= 16 KB
    float bv[4];
#pragma unroll
    for (int j = 0; j < 4; j++) bv[j] = bias[c_base + j * 16];
    bf16_t* h = (bf16_t*)Cout;
#pragma unroll
    for (int i = 0; i < 4; i++) {
#pragma unroll
      for (int j = 0; j < 4; j++) {
        const int col = wc + j * 16 + row16;
#pragma unroll
        for (int r = 0; r < 4; r++) {
          const int e = (wave >> 1) * 16 + quad * 4 + r;
          float v = gelu_exact(gamma * acc[i][j][r] + bv[j]);
          sE[e * 136 + col] = (bf16_t)v;
        }
      }
      __syncthreads();
      {
        // 32 rows x 128 cols = 8 KB per pass; 256 threads x 32 B each
        const int e = tid >> 3, ch = tid & 7;
        const int grow = by * 128 + (e >> 4) * 64 + i * 16 + (e & 15);
        bf16_t* dst = &h[(size_t)grow * N + bx * 128];
        *(bf16x8*)&dst[ch * 8] = *(const bf16x8*)&sE[e * 136 + ch * 8];
        *(bf16x8*)&dst[ch * 8 + 64] = *(const bf16x8*)&sE[e * 136 + ch * 8 + 64];
      }
      __syncthreads();
    }
  } else {
    float* out = (float*)Cout;
#pragma unroll
    for (int j = 0; j < 4; j++) {
      const int col = c_base + j * 16;
      const float bv = bias[col];
#pragma unroll
      for (int i = 0; i < 4; i++) {
#pragma unroll
        for (int r = 0; r < 4; r++) {
          const int row = r_base + i * 16 + r;
          if (row < Mvalid)
            out[(size_t)row * N + col] = gamma * acc[i][j][r] + bv;
        }
      }
    }
  }
}

extern "C" void kernel_launch(void* const* d_in, const int* in_sizes, int n_in,
                              void* d_out, int out_size, void* d_ws, size_t ws_size,
                              hipStream_t stream) {
  const float* x  = (const float*)d_in[0];
  const float* w1 = (const float*)d_in[1];
  const float* b1 = (const float*)d_in[2];
  const float* w2 = (const float*)d_in[3];
  const float* b2 = (const float*)d_in[4];
  float* out = (float*)d_out;

  const int M = 64 * 197;      // 12608
  const int Mpad = 12672;      // 99 * 128
  const int D = 768, H = 3072;
  const int nW = H * D;        // 2359296

  char* ws = (char*)d_ws;
  double* sums = (double*)ws;                      // [0]=sum|w1|, [1]=sum|w2|
  bf16_t* xb  = (bf16_t*)(ws + 256);               // Mpad x D
  bf16_t* w1q = xb + (size_t)Mpad * D;             // H x D
  bf16_t* w2q = w1q + (size_t)H * D;               // D x H
  bf16_t* hb  = w2q + (size_t)D * H;               // Mpad x H

  hipMemsetAsync(sums, 0, 2 * sizeof(double), stream);
  reduce_abs2_kernel<<<512, 256, 0, stream>>>(w1, w2, nW, sums);
  quantize2_kernel<<<(2 * nW / 4) / 256, 256, 0, stream>>>(w1, w2, nW, sums, (double)nW, w1q, w2q);
  cast_pad_kernel<<<((long long)Mpad * D / 4) / 256, 256, 0, stream>>>(
      x, xb, (long long)M * D, (long long)Mpad * D);

  const int gy = Mpad / 128;      // 99
  const int gx1 = H / 128;        // 24
  const int gx2 = D / 128;        // 6
  gemm_bt_kernel<0><<<gx1 * gy, 256, 0, stream>>>(xb, w1q, b1, sums + 0, (double)nW, hb, H, D, M, gx1);
  gemm_bt_kernel<1><<<gx2 * gy, 256, 0, stream>>>(hb, w2q, b2, sums + 1, (double)nW, out, D, H, M, gx2);
}

// Round 6
// 258.446 us; speedup vs baseline: 1.3561x; 1.0165x over previous
//
#include <hip/hip_runtime.h>
#include <hip/hip_bf16.h>
#include <math.h>

typedef __bf16 bf16_t;
typedef __bf16 bf16x8 __attribute__((ext_vector_type(8)));
typedef __bf16 bf16x4 __attribute__((ext_vector_type(4)));
typedef float f32x4 __attribute__((ext_vector_type(4)));

#define QEPS 1e-5

__device__ __forceinline__ void gload_lds16(const void* g, void* l) {
  __builtin_amdgcn_global_load_lds((const __attribute__((address_space(1))) void*)g,
                                   (__attribute__((address_space(3))) void*)l, 16, 0, 0);
}

// exact GELU via A&S 7.1.26 erf (|err| <= 1.5e-7), branchless, v_exp/v_rcp
__device__ __forceinline__ float gelu_exact(float x) {
  float a = x * 0.7071067811865476f;
  float s = fabsf(a);
  float t = __builtin_amdgcn_rcpf(__builtin_fmaf(0.3275911f, s, 1.0f));
  float p = __builtin_fmaf(1.061405429f, t, -1.453152027f);
  p = __builtin_fmaf(p, t, 1.421413741f);
  p = __builtin_fmaf(p, t, -0.284496736f);
  p = __builtin_fmaf(p, t, 0.254829592f);
  p = p * t;
  float e = __expf(-s * s);
  float er = copysignf(__builtin_fmaf(-p, e, 1.0f), a);
  return 0.5f * x * (1.0f + er);
}

// ---- P1: per-block fp64 partial sums of |w|, no atomics, no memset needed ----
// blocks [0,256) -> w1, [256,512) -> w2; part[512]
__global__ void reduce_part_kernel(const float* __restrict__ w1, const float* __restrict__ w2,
                                   int n, double* __restrict__ part) {
  const bool second = blockIdx.x >= 256;
  const float* __restrict__ w = second ? w2 : w1;
  const int b = second ? blockIdx.x - 256 : blockIdx.x;
  double s = 0.0;
  const int stride = 256 * 256 * 4;
  for (int i = (b * 256 + threadIdx.x) * 4; i < n; i += stride) {
    float4 v = *(const float4*)(w + i);
    s += (double)fabsf(v.x) + (double)fabsf(v.y) + (double)fabsf(v.z) + (double)fabsf(v.w);
  }
  for (int off = 32; off > 0; off >>= 1)
    s += __shfl_down(s, off, 64);
  __shared__ double ls[4];
  int lane = threadIdx.x & 63, wv = threadIdx.x >> 6;
  if (lane == 0) ls[wv] = s;
  __syncthreads();
  if (threadIdx.x == 0) part[blockIdx.x] = ls[0] + ls[1] + ls[2] + ls[3];
}

// ---- P2: fused quantize(w1,w2) + cast/pad(x) ----
// blocks [0,QB): quantize (in-block reduce of 256 partials -> g, then 4 elems/thread)
// blocks [QB,QB+CB): cast x -> bf16 with zero pad
// NOTE: gammas must NOT alias part[] — concurrent blocks read part while
// designated blocks write gammas (dispatch order undefined).
__global__ void prep_kernel(const float* __restrict__ w1, const float* __restrict__ w2,
                            const float* __restrict__ x, const double* __restrict__ part,
                            int nW, long long nxv, bf16_t* __restrict__ q1,
                            bf16_t* __restrict__ q2, bf16_t* __restrict__ xb,
                            double* __restrict__ gammas) {
  const int QB = (nW >> 1) >> 8;      // 2*nW/4/256 = 4608
  const int tid = threadIdx.x;
  if (blockIdx.x < QB) {
    const int half = QB >> 1;
    const bool second = blockIdx.x >= half;
    double p = part[(second ? 256 : 0) + tid];
    for (int off = 32; off > 0; off >>= 1)
      p += __shfl_down(p, off, 64);
    __shared__ double red[4];
    if ((tid & 63) == 0) red[tid >> 6] = p;
    __syncthreads();
    const double g = (red[0] + red[1] + red[2] + red[3]) / (double)nW + QEPS;
    if (tid == 0 && blockIdx.x == (second ? half : 0)) gammas[second ? 1 : 0] = g;
    const double rg = 1.0 / g;
    const int idx = blockIdx.x * 256 + tid - (second ? (nW >> 2) : 0);
    const float4 v = ((const float4*)(second ? w2 : w1))[idx];
    bf16x4 r;
    r[0] = (bf16_t)(float)fmin(1.0, fmax(-1.0, rint((double)v.x * rg)));
    r[1] = (bf16_t)(float)fmin(1.0, fmax(-1.0, rint((double)v.y * rg)));
    r[2] = (bf16_t)(float)fmin(1.0, fmax(-1.0, rint((double)v.z * rg)));
    r[3] = (bf16_t)(float)fmin(1.0, fmax(-1.0, rint((double)v.w * rg)));
    ((bf16x4*)(second ? q2 : q1))[idx] = r;
  } else {
    long long i = ((long long)(blockIdx.x - QB) * 256 + tid) * 4;
    bf16x4 r;
    if (i < nxv) {
      float4 v = *(const float4*)(x + i);
      r[0] = (bf16_t)v.x; r[1] = (bf16_t)v.y; r[2] = (bf16_t)v.z; r[3] = (bf16_t)v.w;
    } else {
      r[0] = (bf16_t)0.0f; r[1] = (bf16_t)0.0f; r[2] = (bf16_t)0.0f; r[3] = (bf16_t)0.0f;
    }
    *(bf16x4*)(xb + i) = r;
  }
}

// ---- C = A(M x K) * B(N x K)^T, bf16 MFMA 16x16x32, 128 x BN tile, BK=64 ----
// 1D grid, XCD-chunked tile mapping (block f -> XCD f%8, contiguous row-major
// chunk per XCD for L2 locality of A row-tiles).
// LDS: row stride 64 elems; 16B chunk c of row r at slot (c ^ (r&7)) -> conflict-free.
// EPI==0 (BN=128): h = bf16(gelu(gamma*acc + bias)), LDS-staged coalesced stores
// EPI==1: out = fp32(gamma*acc + bias), rows < Mvalid
template <int EPI, int BN>
__global__ __launch_bounds__(256, 4)
void gemm_bt_kernel(const bf16_t* __restrict__ A, const bf16_t* __restrict__ B,
                    const float* __restrict__ bias, const double* __restrict__ gptr,
                    void* __restrict__ Cout, int N, int K, int Mvalid, int gx) {
  constexpr int NJ = BN / 32;         // b-frags per wave (128->4, 64->2)
  __shared__ bf16_t sA[128 * 64];     // 16 KB
  __shared__ bf16_t sB[BN * 64];      // 16 or 8 KB

  // XCD-chunked tile id
  const int G = gridDim.x;
  const int f = blockIdx.x;
  const int xcd = f & 7;
  const int idx = f >> 3;
  const int q8 = G >> 3, r8 = G & 7;
  const int t = xcd * q8 + (xcd < r8 ? xcd : r8) + idx;
  const int bx = t % gx;
  const int by = t / gx;

  const int tid = threadIdx.x;
  const int lane = tid & 63;
  const int wave = tid >> 6;            // 4 waves, 2x2 regions of 64 x (BN/2)
  const int wr = (wave >> 1) * 64;
  const int wc = (wave & 1) * (BN / 2);
  const int row16 = lane & 15;
  const int quad = lane >> 4;

  const size_t Ks = (size_t)K;
  const int cg = (tid & 7) ^ ((tid >> 3) & 7);   // swizzled global 16B chunk
  const bf16_t* gA = A + ((size_t)(by * 128 + (tid >> 3))) * Ks + (size_t)cg * 8;
  const bf16_t* gB = B + ((size_t)(bx * BN + (tid >> 3))) * Ks + (size_t)cg * 8;
  bf16_t* lA = sA + wave * 512;   // + n*2048 per 32-row round; builtin adds lane*16B
  bf16_t* lB = sB + wave * 512;

  f32x4 acc[4][NJ] = {};

  for (int k0 = 0; k0 < K; k0 += 64) {
#pragma unroll
    for (int n = 0; n < 4; n++)
      gload_lds16(gA + (size_t)(n * 32) * Ks, lA + n * 2048);
#pragma unroll
    for (int n = 0; n < BN / 32; n++)
      gload_lds16(gB + (size_t)(n * 32) * Ks, lB + n * 2048);
    gA += 64;
    gB += 64;
    __syncthreads();

#pragma unroll
    for (int kk = 0; kk < 2; kk++) {
      bf16x8 afr[4], bfr[NJ];
      const int swz = ((kk * 4 + quad) ^ (row16 & 7)) * 8;
#pragma unroll
      for (int i = 0; i < 4; i++)
        afr[i] = *(const bf16x8*)&sA[(wr + i * 16 + row16) * 64 + swz];
#pragma unroll
      for (int j = 0; j < NJ; j++)
        bfr[j] = *(const bf16x8*)&sB[(wc + j * 16 + row16) * 64 + swz];
#pragma unroll
      for (int i = 0; i < 4; i++)
#pragma unroll
        for (int j = 0; j < NJ; j++)
          acc[i][j] = __builtin_amdgcn_mfma_f32_16x16x32_bf16(afr[i], bfr[j], acc[i][j], 0, 0, 0);
    }
    __syncthreads();
  }

  const float gamma = (float)gptr[0];
  const int c_base = bx * BN + wc + row16;     // C/D: col = lane&15
  const int r_base = by * 128 + wr + quad * 4; // row = quad*4 + reg

  if constexpr (EPI == 0) {
    // LDS-staged coalesced bf16 stores, sE aliased onto sA (done with main loop)
    bf16_t* sE = sA;   // 32 x 136 = 8.5 KB <= 16 KB
    float bv[NJ];
#pragma unroll
    for (int j = 0; j < NJ; j++) bv[j] = bias[c_base + j * 16];
    bf16_t* h = (bf16_t*)Cout;
#pragma unroll
    for (int i = 0; i < 4; i++) {
#pragma unroll
      for (int j = 0; j < NJ; j++) {
        const int col = wc + j * 16 + row16;
#pragma unroll
        for (int r = 0; r < 4; r++) {
          const int e = (wave >> 1) * 16 + quad * 4 + r;
          float v = gelu_exact(gamma * acc[i][j][r] + bv[j]);
          sE[e * 136 + col] = (bf16_t)v;
        }
      }
      __syncthreads();
      {
        // 32 rows x 128 cols = 8 KB per pass; 256 threads x 32 B each
        const int e = tid >> 3, ch = tid & 7;
        const int grow = by * 128 + (e >> 4) * 64 + i * 16 + (e & 15);
        bf16_t* dst = &h[(size_t)grow * N + bx * BN];
        *(bf16x8*)&dst[ch * 8] = *(const bf16x8*)&sE[e * 136 + ch * 8];
        *(bf16x8*)&dst[ch * 8 + 64] = *(const bf16x8*)&sE[e * 136 + ch * 8 + 64];
      }
      __syncthreads();
    }
  } else {
    float* out = (float*)Cout;
#pragma unroll
    for (int j = 0; j < NJ; j++) {
      const int col = c_base + j * 16;
      const float bv = bias[col];
#pragma unroll
      for (int i = 0; i < 4; i++) {
#pragma unroll
        for (int r = 0; r < 4; r++) {
          const int row = r_base + i * 16 + r;
          if (row < Mvalid)
            out[(size_t)row * N + col] = gamma * acc[i][j][r] + bv;
        }
      }
    }
  }
}

extern "C" void kernel_launch(void* const* d_in, const int* in_sizes, int n_in,
                              void* d_out, int out_size, void* d_ws, size_t ws_size,
                              hipStream_t stream) {
  const float* x  = (const float*)d_in[0];
  const float* w1 = (const float*)d_in[1];
  const float* b1 = (const float*)d_in[2];
  const float* w2 = (const float*)d_in[3];
  const float* b2 = (const float*)d_in[4];
  float* out = (float*)d_out;

  const int M = 64 * 197;      // 12608
  const int Mpad = 12672;      // 99 * 128
  const int D = 768, H = 3072;
  const int nW = H * D;        // 2359296

  char* ws = (char*)d_ws;
  double* part = (double*)ws;                      // [512] partials: ws[0,4096)
  double* gammas = (double*)(ws + 4096);           // [2] — own cacheline, NO overlap with part
  bf16_t* xb  = (bf16_t*)(ws + 4096 + 256);        // Mpad x D
  bf16_t* w1q = xb + (size_t)Mpad * D;             // H x D
  bf16_t* w2q = w1q + (size_t)H * D;               // D x H
  bf16_t* hb  = w2q + (size_t)D * H;               // Mpad x H

  reduce_part_kernel<<<512, 256, 0, stream>>>(w1, w2, nW, part);
  const int QB = (nW >> 1) >> 8;                   // 4608
  const int CB = (int)(((long long)Mpad * D / 4) / 256);  // 9504
  prep_kernel<<<QB + CB, 256, 0, stream>>>(w1, w2, x, part, nW, (long long)M * D,
                                           w1q, w2q, xb, gammas);

  const int gy = Mpad / 128;      // 99
  const int gx1 = H / 128;        // 24
  const int gx2 = D / 64;         // 12
  gemm_bt_kernel<0, 128><<<gx1 * gy, 256, 0, stream>>>(xb, w1q, b1, gammas + 0, hb, H, D, M, gx1);
  gemm_bt_kernel<1, 64><<<gx2 * gy, 256, 0, stream>>>(hb, w2q, b2, gammas + 1, out, D, H, M, gx2);
}